// Round 2
// baseline (324.345 us; speedup 1.0000x reference)
//
#include <hip/hip_runtime.h>
#include <cstddef>

#define NPIX 4096
#define CDIM 512

typedef _Float16 half8  __attribute__((ext_vector_type(8)));
typedef _Float16 half4v __attribute__((ext_vector_type(4)));
typedef float    f32x4  __attribute__((ext_vector_type(4)));

__device__ __forceinline__ void gl_lds16(const void* g, void* l) {
    __builtin_amdgcn_global_load_lds(
        (const __attribute__((address_space(1))) void*)g,
        (__attribute__((address_space(3))) void*)l, 16, 0, 0);
}

// -------------------------------------------------------------------------
// prep: combined weight prep.
//   blocks 0..95 : wA/wB/wC fp32 [128][512] -> frag-blocked fp16 Wh
//   blocks 96..127: wProj fp32 [512][128] -> plain fp16 WpH [512][128]
// -------------------------------------------------------------------------
__global__ __launch_bounds__(256)
void prep(const float* __restrict__ wA, const float* __restrict__ wB,
          const float* __restrict__ wC, const float* __restrict__ wProj,
          _Float16* __restrict__ Wh, _Float16* __restrict__ WpH)
{
    if (blockIdx.x < 96) {
        const int gid  = blockIdx.x * 256 + threadIdx.x;   // 0..24575
        const int lane = gid & 63;
        const int frag = gid >> 6;                         // 0..383
        const int msub = frag & 7, kt = (frag >> 3) & 15, mt = frag >> 7;
        const float* __restrict__ W = (mt == 0) ? wA : (mt == 1) ? wB : wC;
        const int m  = msub * 16 + (lane & 15);
        const int c0 = kt * 32 + ((lane >> 4) << 3);
        const float* src = W + m * CDIM + c0;
        union { _Float16 h[8]; float4 f; } u;
#pragma unroll
        for (int j = 0; j < 8; ++j) u.h[j] = (_Float16)src[j];
        *(float4*)(Wh + (size_t)frag * 512 + lane * 8) = u.f;
    } else {
        const int gid = (blockIdx.x - 96) * 256 + threadIdx.x;  // 0..8191
        const int i8  = gid * 8;
        float4 a = *(const float4*)(wProj + i8);
        float4 b = *(const float4*)(wProj + i8 + 4);
        union { _Float16 h[8]; float4 f; } u;
        u.h[0]=(_Float16)a.x; u.h[1]=(_Float16)a.y; u.h[2]=(_Float16)a.z; u.h[3]=(_Float16)a.w;
        u.h[4]=(_Float16)b.x; u.h[5]=(_Float16)b.y; u.h[6]=(_Float16)b.z; u.h[7]=(_Float16)b.w;
        *(float4*)(WpH + i8) = u.f;
    }
}

// -------------------------------------------------------------------------
// conv_mfma: P[b, mt*128:+128, n] (fp16) = W_mt @ x[b]  via fp16 MFMA.
// Operand-swapped MFMA (D^T layout): thread holds 4 consecutive n for a
// fixed m -> packed 8B stores instead of 64x2B scalar stores.
// -------------------------------------------------------------------------
__global__ __launch_bounds__(256)
void conv_mfma(const float* __restrict__ x, const _Float16* __restrict__ Wh,
               _Float16* __restrict__ P)
{
    const int nt = blockIdx.x, mt = blockIdx.y, b = blockIdx.z;
    const int tid  = threadIdx.x;
    const int wave = tid >> 6, lane = tid & 63;
    const int wm = wave >> 1, wn = wave & 1;

    __shared__ alignas(16) _Float16 sA[4096];        // 8 frag-blocks x 512
    __shared__ alignas(16) _Float16 sB[128 * 40];    // [n][32k + 8 pad], swizzled

    f32x4 acc[4][4];
#pragma unroll
    for (int i = 0; i < 4; ++i)
#pragma unroll
        for (int j = 0; j < 4; ++j)
#pragma unroll
            for (int e = 0; e < 4; ++e) acc[i][j][e] = 0.f;

    const int n0 = (tid & 31) << 2;
    const int k0 = (tid >> 5) << 2;
    const float* xb = x + ((size_t)b << 21) + (nt << 7) + n0;
    const _Float16* WhB = Wh + (size_t)mt * 128 * 512;

    for (int kt = 0; kt < 16; ++kt) {
#pragma unroll
        for (int s = 0; s < 2; ++s) {
            const int frag = wave + (s << 2);
            gl_lds16(WhB + ((size_t)kt * 8 + frag) * 512 + lane * 8, &sA[frag * 512]);
        }
        const float* xs = xb + (size_t)(kt * 32 + k0) * NPIX;
        float ld[4][4];
        *(float4*)&ld[0][0] = *(const float4*)(xs);
        *(float4*)&ld[1][0] = *(const float4*)(xs + NPIX);
        *(float4*)&ld[2][0] = *(const float4*)(xs + 2 * NPIX);
        *(float4*)&ld[3][0] = *(const float4*)(xs + 3 * NPIX);
#pragma unroll
        for (int c = 0; c < 4; ++c) {
            const int n    = n0 + c;
            const int blkh = ((k0 >> 2) ^ (((n >> 4) & 3) << 1)) << 2;
            union { _Float16 h[4]; float2 f; } u;
            u.h[0] = (_Float16)ld[0][c];
            u.h[1] = (_Float16)ld[1][c];
            u.h[2] = (_Float16)ld[2][c];
            u.h[3] = (_Float16)ld[3][c];
            *(float2*)&sB[n * 40 + blkh] = u.f;
        }
        __syncthreads();

        half8 av[4], bv[4];
#pragma unroll
        for (int i = 0; i < 4; ++i)
            av[i] = *(const half8*)&sA[(((wm << 2) + i) << 9) + (lane << 3)];
#pragma unroll
        for (int j = 0; j < 4; ++j) {
            const int nj = (wn << 6) + (j << 4) + (lane & 15);
            const int qs = ((lane >> 4) ^ ((nj >> 4) & 3)) << 3;
            bv[j] = *(const half8*)&sB[nj * 40 + qs];
        }
        // swapped operands: D row = n (x), col = m (W)
#pragma unroll
        for (int i = 0; i < 4; ++i)
#pragma unroll
            for (int j = 0; j < 4; ++j)
                acc[i][j] = __builtin_amdgcn_mfma_f32_16x16x32_f16(bv[j], av[i], acc[i][j], 0, 0, 0);
        __syncthreads();
    }

    // D^T epilogue: m = col (lane&15), n = row pack of 4 -> 8B stores
    _Float16* Pb = P + (((size_t)b * 384 + mt * 128) << 12);
#pragma unroll
    for (int i = 0; i < 4; ++i) {
        const int m = (wm << 6) + (i << 4) + (lane & 15);
        _Float16* prow = Pb + (size_t)m * NPIX + (nt << 7) + (wn << 6) + ((lane >> 4) << 2);
#pragma unroll
        for (int j = 0; j < 4; ++j) {
            union { _Float16 h[4]; float2 f; } u;
#pragma unroll
            for (int r = 0; r < 4; ++r) u.h[r] = (_Float16)acc[i][j][r];
            *(float2*)(prow + (j << 4)) = u.f;
        }
    }
}

// -------------------------------------------------------------------------
// softmax_rows: fp16 in/out, fp32 math. Rows 0..127 (A) and 256..383 (Cs).
// -------------------------------------------------------------------------
__global__ __launch_bounds__(256)
void softmax_rows(_Float16* __restrict__ P)
{
    const int blk = blockIdx.x;            // 0..4095
    const int b   = blk >> 8;
    const int r   = blk & 255;
    const int m   = (r < 128) ? r : (r + 128);
    _Float16* row = P + (((size_t)b * 384 + m) << 12);
    const int tid = threadIdx.x;

    half8 h[2];
    float v[16];
    h[0] = *(const half8*)(row + tid * 16);
    h[1] = *(const half8*)(row + tid * 16 + 8);
    float mx = -3.402823466e38f;
#pragma unroll
    for (int j = 0; j < 16; ++j) { v[j] = (float)h[j >> 3][j & 7]; mx = fmaxf(mx, v[j]); }
#pragma unroll
    for (int o = 32; o > 0; o >>= 1) mx = fmaxf(mx, __shfl_xor(mx, o));
    __shared__ float redm[4];
    __shared__ float reds[4];
    const int wid = tid >> 6, lane = tid & 63;
    if (lane == 0) redm[wid] = mx;
    __syncthreads();
    mx = fmaxf(fmaxf(redm[0], redm[1]), fmaxf(redm[2], redm[3]));

    float s = 0.f;
#pragma unroll
    for (int j = 0; j < 16; ++j) { v[j] = __expf(v[j] - mx); s += v[j]; }
#pragma unroll
    for (int o = 32; o > 0; o >>= 1) s += __shfl_xor(s, o);
    if (lane == 0) reds[wid] = s;
    __syncthreads();
    s = (reds[0] + reds[1]) + (reds[2] + reds[3]);
    const float inv = 1.f / s;
#pragma unroll
    for (int j = 0; j < 16; ++j) h[j >> 3][j & 7] = (_Float16)(v[j] * inv);
    *(half8*)(row + tid * 16)     = h[0];
    *(half8*)(row + tid * 16 + 8) = h[1];
}

// -------------------------------------------------------------------------
// g_partial_mfma: Gp[b][kc][g][h] = A[g, chunk] . Bf[h, chunk]  (= G^T partial)
// Swapped MFMA: D row = h, col = g -> f32x4 stores along h.
// -------------------------------------------------------------------------
__global__ __launch_bounds__(256)
void g_partial_mfma(const _Float16* __restrict__ P, float* __restrict__ Gp)
{
    const int kc = blockIdx.x, b = blockIdx.y;
    const int tid  = threadIdx.x;
    const int wave = tid >> 6, lane = tid & 63;
    const int wm = wave >> 1, wn = wave & 1;

    const _Float16* Pa = P + ((size_t)b * 384 << 12);        // softmaxed A rows
    const _Float16* Pf = Pa + ((size_t)128 << 12);           // Bf rows

    f32x4 acc[4][4];
#pragma unroll
    for (int i = 0; i < 4; ++i)
#pragma unroll
        for (int j = 0; j < 4; ++j)
#pragma unroll
            for (int e = 0; e < 4; ++e) acc[i][j][e] = 0.f;

    const int klane = ((lane >> 4) << 3);
    const int rlane = lane & 15;
#pragma unroll 2
    for (int kt = 0; kt < 8; ++kt) {
        const int k = (kc << 8) + (kt << 5) + klane;
        half8 av[4], bv[4];
#pragma unroll
        for (int i = 0; i < 4; ++i)
            av[i] = *(const half8*)(Pa + ((size_t)((wm << 6) + (i << 4) + rlane) << 12) + k);
#pragma unroll
        for (int j = 0; j < 4; ++j)
            bv[j] = *(const half8*)(Pf + ((size_t)((wn << 6) + (j << 4) + rlane) << 12) + k);
#pragma unroll
        for (int i = 0; i < 4; ++i)
#pragma unroll
            for (int j = 0; j < 4; ++j)
                acc[i][j] = __builtin_amdgcn_mfma_f32_16x16x32_f16(bv[j], av[i], acc[i][j], 0, 0, 0);
    }

    float* O = Gp + (((size_t)b * 16 + kc) << 14);
#pragma unroll
    for (int i = 0; i < 4; ++i) {
        const int g = (wm << 6) + (i << 4) + rlane;
        float* orow = O + (size_t)g * 128 + (wn << 6) + ((lane >> 4) << 2);
#pragma unroll
        for (int j = 0; j < 4; ++j)
            *(f32x4*)(orow + (j << 4)) = acc[i][j];
    }
}

// -------------------------------------------------------------------------
// g_reduce_cvt: Gt[b][g][h] (fp16, = G^T) = sum of 16 fp32 partials.
// -------------------------------------------------------------------------
__global__ __launch_bounds__(256)
void g_reduce_cvt(const float* __restrict__ Gp, _Float16* __restrict__ Gt)
{
    const int gid  = blockIdx.x * 256 + threadIdx.x;  // 0..32767
    const int i8   = gid * 8;
    const int b    = i8 >> 14;
    const int rr   = i8 & 16383;
    const float* base = Gp + ((size_t)b << 18) + rr;
    float s[8];
#pragma unroll
    for (int e = 0; e < 8; ++e) s[e] = 0.f;
#pragma unroll
    for (int kc = 0; kc < 16; ++kc) {
        float4 v0 = *(const float4*)(base + ((size_t)kc << 14));
        float4 v1 = *(const float4*)(base + ((size_t)kc << 14) + 4);
        s[0]+=v0.x; s[1]+=v0.y; s[2]+=v0.z; s[3]+=v0.w;
        s[4]+=v1.x; s[5]+=v1.y; s[6]+=v1.z; s[7]+=v1.w;
    }
    union { _Float16 h[8]; float4 f; } u;
#pragma unroll
    for (int e = 0; e < 8; ++e) u.h[e] = (_Float16)s[e];
    *(float4*)(Gt + ((size_t)b << 14) + rr) = u.f;
}

// -------------------------------------------------------------------------
// proj_mfma: Mh[b][c][g] = sum_h WpH[c][h] * Gt[g][h].
// Swapped MFMA: D row = g, col = c -> packed 8B stores along g.
// -------------------------------------------------------------------------
__global__ __launch_bounds__(256)
void proj_mfma(const _Float16* __restrict__ WpH, const _Float16* __restrict__ Gt,
               _Float16* __restrict__ Mh)
{
    const int ct = blockIdx.x, b = blockIdx.y;
    const int tid  = threadIdx.x;
    const int wave = tid >> 6, lane = tid & 63;
    const int wm = wave >> 1, wn = wave & 1;

    f32x4 acc[4][4];
#pragma unroll
    for (int i = 0; i < 4; ++i)
#pragma unroll
        for (int j = 0; j < 4; ++j)
#pragma unroll
            for (int e = 0; e < 4; ++e) acc[i][j][e] = 0.f;

    const int klane = ((lane >> 4) << 3);
    const int rlane = lane & 15;
    const _Float16* Gb = Gt + ((size_t)b << 14);
#pragma unroll
    for (int kt = 0; kt < 4; ++kt) {
        const int k = (kt << 5) + klane;
        half8 av[4], bv[4];
#pragma unroll
        for (int i = 0; i < 4; ++i)
            av[i] = *(const half8*)(WpH + (size_t)((ct << 7) + (wm << 6) + (i << 4) + rlane) * 128 + k);
#pragma unroll
        for (int j = 0; j < 4; ++j)
            bv[j] = *(const half8*)(Gb + (size_t)((wn << 6) + (j << 4) + rlane) * 128 + k);
#pragma unroll
        for (int i = 0; i < 4; ++i)
#pragma unroll
            for (int j = 0; j < 4; ++j)
                acc[i][j] = __builtin_amdgcn_mfma_f32_16x16x32_f16(bv[j], av[i], acc[i][j], 0, 0, 0);
    }

    _Float16* Mb = Mh + ((size_t)b << 16);
#pragma unroll
    for (int i = 0; i < 4; ++i) {
        const int c = (ct << 7) + (wm << 6) + (i << 4) + rlane;
        _Float16* mrow = Mb + (size_t)c * 128 + (wn << 6) + ((lane >> 4) << 2);
#pragma unroll
        for (int j = 0; j < 4; ++j) {
            union { _Float16 h[4]; float2 f; } u;
#pragma unroll
            for (int r = 0; r < 4; ++r) u.h[r] = (_Float16)acc[i][j][r];
            *(float2*)(mrow + (j << 4)) = u.f;
        }
    }
}

// -------------------------------------------------------------------------
// final_mfma: out = BN(Mh[b] @ Cs[b]).
// Swapped MFMA: D row = n, col = c -> full float4 (16B) stores along n,
// BN scale/shift computed once per c-tile.
// -------------------------------------------------------------------------
__global__ __launch_bounds__(256)
void final_mfma(const _Float16* __restrict__ P, const _Float16* __restrict__ Mh,
                const float* __restrict__ gamma, const float* __restrict__ beta,
                const float* __restrict__ mean,  const float* __restrict__ var,
                float* __restrict__ out)
{
    const int nt = blockIdx.x, ct = blockIdx.y, b = blockIdx.z;
    const int tid  = threadIdx.x;
    const int wave = tid >> 6, lane = tid & 63;
    const int wm = wave >> 1, wn = wave & 1;

    __shared__ alignas(16) _Float16 sB[128 * 40];

    f32x4 acc[4][4];
#pragma unroll
    for (int i = 0; i < 4; ++i)
#pragma unroll
        for (int j = 0; j < 4; ++j)
#pragma unroll
            for (int e = 0; e < 4; ++e) acc[i][j][e] = 0.f;

    const int n0 = (tid & 31) << 2;
    const int k0 = (tid >> 5) << 2;
    const int klane = ((lane >> 4) << 3);
    const int rlane = lane & 15;
    const _Float16* Cs  = P + (((size_t)b * 384 + 256) << 12) + (nt << 7) + n0;
    const _Float16* MhB = Mh + ((size_t)b << 16) + ((size_t)(ct << 7) << 7);

    for (int kt = 0; kt < 4; ++kt) {
        const _Float16* cs = Cs + ((size_t)((kt << 5) + k0) << 12);
        half4v ld0 = *(const half4v*)(cs);
        half4v ld1 = *(const half4v*)(cs + NPIX);
        half4v ld2 = *(const half4v*)(cs + 2 * NPIX);
        half4v ld3 = *(const half4v*)(cs + 3 * NPIX);
#pragma unroll
        for (int c = 0; c < 4; ++c) {
            const int n    = n0 + c;
            const int blkh = ((k0 >> 2) ^ (((n >> 4) & 3) << 1)) << 2;
            half4v col = { ld0[c], ld1[c], ld2[c], ld3[c] };
            *(half4v*)&sB[n * 40 + blkh] = col;
        }
        __syncthreads();

        half8 av[4], bv[4];
#pragma unroll
        for (int i = 0; i < 4; ++i)
            av[i] = *(const half8*)(MhB + (size_t)((wm << 6) + (i << 4) + rlane) * 128 + (kt << 5) + klane);
#pragma unroll
        for (int j = 0; j < 4; ++j) {
            const int nj = (wn << 6) + (j << 4) + rlane;
            const int qs = ((lane >> 4) ^ ((nj >> 4) & 3)) << 3;
            bv[j] = *(const half8*)&sB[nj * 40 + qs];
        }
#pragma unroll
        for (int i = 0; i < 4; ++i)
#pragma unroll
            for (int j = 0; j < 4; ++j)
                acc[i][j] = __builtin_amdgcn_mfma_f32_16x16x32_f16(bv[j], av[i], acc[i][j], 0, 0, 0);
        __syncthreads();
    }

    // D^T epilogue: c = col (lane&15), n = row pack of 4 -> float4 stores
    float* ob = out + ((size_t)b << 21);
#pragma unroll
    for (int i = 0; i < 4; ++i) {
        const int c   = (ct << 7) + (wm << 6) + (i << 4) + rlane;
        const float s = gamma[c] * rsqrtf(var[c] + 1e-5f);
        const float t = fmaf(-mean[c], s, beta[c]);
        float* row = ob + ((size_t)c << 12) + (nt << 7) + (wn << 6) + ((lane >> 4) << 2);
#pragma unroll
        for (int j = 0; j < 4; ++j) {
            f32x4 v;
#pragma unroll
            for (int r = 0; r < 4; ++r) v[r] = fmaf(acc[i][j][r], s, t);
            *(f32x4*)(row + (j << 4)) = v;
        }
    }
}

// -------------------------------------------------------------------------
extern "C" void kernel_launch(void* const* d_in, const int* in_sizes, int n_in,
                              void* d_out, int out_size, void* d_ws, size_t ws_size,
                              hipStream_t stream)
{
    const float* x     = (const float*)d_in[0];
    const float* wA    = (const float*)d_in[1];
    const float* wB    = (const float*)d_in[2];
    const float* wC    = (const float*)d_in[3];
    const float* wProj = (const float*)d_in[4];
    const float* gamma = (const float*)d_in[5];
    const float* beta  = (const float*)d_in[6];
    const float* mean  = (const float*)d_in[7];
    const float* var   = (const float*)d_in[8];
    float* out = (float*)d_out;

    char* ws = (char*)d_ws;
    _Float16* P   = (_Float16*)(ws);                   // 16*384*4096*2 = 50331648
    float*    Gp  = (float*)(ws + 50331648);           // 16*16*16384*4 = 16777216
    _Float16* Gt  = (_Float16*)(ws + 67108864);        // 16*16384*2    =   524288
    _Float16* WpH = (_Float16*)(ws + 67633152);        // 512*128*2     =   131072
    _Float16* Mh  = (_Float16*)(ws + 67764224);        // 16*512*128*2  =  2097152
    _Float16* Wh  = (_Float16*)(ws + 69861376);        // 384*512*2     =   393216
    // total ws use: 70254592 bytes

    prep          <<<dim3(128),       256, 0, stream>>>(wA, wB, wC, wProj, Wh, WpH);
    conv_mfma     <<<dim3(32, 3, 16), 256, 0, stream>>>(x, Wh, P);
    softmax_rows  <<<dim3(4096),      256, 0, stream>>>(P);
    g_partial_mfma<<<dim3(16, 16),    256, 0, stream>>>(P, Gp);
    g_reduce_cvt  <<<dim3(128),       256, 0, stream>>>(Gp, Gt);
    proj_mfma     <<<dim3(4, 16),     256, 0, stream>>>(WpH, Gt, Mh);
    final_mfma    <<<dim3(32, 4, 16), 256, 0, stream>>>(P, Mh, gamma, beta, mean, var, out);
}